// Round 3
// baseline (261.314 us; speedup 1.0000x reference)
//
#include <hip/hip_runtime.h>
#include <hip/hip_fp16.h>

#define N_NODES 100000
#define N_EDGES 1600000
#define HDIM 64
#define NPB 512                                  // nodes per bucket (pow2)
#define NPB_SHIFT 9
#define NBUCK 196                                // ceil(100000/512)
#define CAP 16384                                // per-bucket slot capacity
#define NCHUNK 512                               // place blocks (2/CU for TLP)
#define CHUNK (N_EDGES / NCHUNK)                 // 3125 edges/block
#define DROWS 64                                 // dense rows/block (512 threads, 8 lanes/row)
#define DENSE_BLOCKS ((N_NODES + DROWS - 1) / DROWS)   // 1563

typedef float f4v __attribute__((ext_vector_type(4)));

// ---------------- K0: init global bucket cursors ----------------
__global__ void init_kernel(int* __restrict__ gcurD, int* __restrict__ gcurS) {
    int t = threadIdx.x;
    if (t < NBUCK) {
        gcurD[t] = t * CAP;
        gcurS[t] = t * CAP;
    }
}

__device__ inline uint2 f4_to_h4(float x, float y, float z, float w) {
    __half2 lo = __floats2half2_rn(x, y);
    __half2 hi = __floats2half2_rn(z, w);
    uint2 r;
    r.x = *(unsigned*)&lo;
    r.y = *(unsigned*)&hi;
    return r;
}

// ---------------- K1: place edges into fixed-capacity bucket regions (SOLO) ----------------
// Run reservation: one global atomic per (chunk,bucket); scatter via LDS cursors.
// bufD entry: src | (local_dst << 17)
__global__ void place_kernel(const int* __restrict__ src, const int* __restrict__ dst,
                             int* __restrict__ gcurD, int* __restrict__ gcurS,
                             unsigned int* __restrict__ bufD, unsigned short* __restrict__ bufS) {
    __shared__ int hD[NBUCK], hS[NBUCK], curD[NBUCK], curS[NBUCK];
    int t = threadIdx.x, blk = blockIdx.x;
    for (int i = t; i < NBUCK; i += 256) { hD[i] = 0; hS[i] = 0; }
    __syncthreads();
    int e0 = blk * CHUNK;
    // pass 1: count (chunk is ~25 KB -> L1/L2 hot for pass 2)
    for (int i = t; i < CHUNK; i += 256) {
        atomicAdd(&hD[dst[e0 + i] >> NPB_SHIFT], 1);
        atomicAdd(&hS[src[e0 + i] >> NPB_SHIFT], 1);
    }
    __syncthreads();
    // reserve runs
    for (int i = t; i < NBUCK; i += 256) {
        curD[i] = hD[i] ? atomicAdd(&gcurD[i], hD[i]) : 0;
        curS[i] = hS[i] ? atomicAdd(&gcurS[i], hS[i]) : 0;
    }
    __syncthreads();
    // pass 2: scatter
    for (int i = t; i < CHUNK; i += 256) {
        int s = src[e0 + i], d = dst[e0 + i];
        int pd = atomicAdd(&curD[d >> NPB_SHIFT], 1);
        bufD[pd] = (unsigned)s | ((unsigned)(d & (NPB - 1)) << 17);
        int ps = atomicAdd(&curS[s >> NPB_SHIFT], 1);
        bufS[ps] = (unsigned short)(s & (NPB - 1));
    }
}

// ---------------- shfl-dense body (512 threads, 64 rows/block): hw(fp16) = h @ W ----------------
// lane gl owns cols [8gl, 8gl+8); A-row broadcast via intra-wave __shfl; only Wlds in LDS.
__device__ __forceinline__ void dense_body512(int t, int r0,
                                              const float* __restrict__ h,
                                              const float* __restrict__ W,
                                              uint2* __restrict__ hw, int n) {
    __shared__ float Wlds[HDIM * HDIM];     // 16 KB
    for (int i = t; i < HDIM * HDIM / 4; i += 512)
        ((f4v*)Wlds)[i] = ((const f4v*)W)[i];

    int r = t >> 3, gl = t & 7;             // 64 rows, 8 lanes/row
    int row = r0 + r;
    f4v a0 = {0.f, 0.f, 0.f, 0.f}, a1 = a0;
    if (row < n) {
        a0 = __builtin_nontemporal_load((const f4v*)h + (long long)row * 16 + gl * 2 + 0);
        a1 = __builtin_nontemporal_load((const f4v*)h + (long long)row * 16 + gl * 2 + 1);
    }
    __syncthreads();

    float acc0 = 0.f, acc1 = 0.f, acc2 = 0.f, acc3 = 0.f;
    float acc4 = 0.f, acc5 = 0.f, acc6 = 0.f, acc7 = 0.f;
    int gbase = (t & 63) & 56;              // 8-lane group base within wave

#pragma unroll
    for (int k = 0; k < HDIM; ++k) {
        float av = ((k >> 2) & 1) ? a1[k & 3] : a0[k & 3];   // static component
        float ak = __shfl(av, gbase + (k >> 3), 64);
        f4v w0 = ((const f4v*)Wlds)[k * 16 + gl * 2 + 0];
        f4v w1 = ((const f4v*)Wlds)[k * 16 + gl * 2 + 1];
        acc0 = fmaf(ak, w0.x, acc0); acc1 = fmaf(ak, w0.y, acc1);
        acc2 = fmaf(ak, w0.z, acc2); acc3 = fmaf(ak, w0.w, acc3);
        acc4 = fmaf(ak, w1.x, acc4); acc5 = fmaf(ak, w1.y, acc5);
        acc6 = fmaf(ak, w1.z, acc6); acc7 = fmaf(ak, w1.w, acc7);
    }

    if (row < n) {
        hw[(long long)row * 16 + gl * 2 + 0] = f4_to_h4(acc0, acc1, acc2, acc3);
        hw[(long long)row * 16 + gl * 2 + 1] = f4_to_h4(acc4, acc5, acc6, acc7);
    }
}

// ---------------- K2: per-bucket fine stage ∥ dense layer-1 ----------------
// blocks [0,196): dst buckets -> counting sort to csr_src, offs, inv_in
// blocks [196,392): src buckets -> counts -> inv_out
// blocks [392, 392+1563): dense layer-1 (fills the ~80% of CUs bucket leaves idle)
// LDS = 6KB (bucket) + 16KB (Wlds) = 22.5KB @ 512thr -> 4 blocks/CU = the wave limit anyway.
__global__ void bucket_dense_kernel(const unsigned int* __restrict__ bufD,
                                    const unsigned short* __restrict__ bufS,
                                    const int* __restrict__ gcurD, const int* __restrict__ gcurS,
                                    int* __restrict__ csr_src, int2* __restrict__ offs,
                                    float* __restrict__ inv_in, float* __restrict__ inv_out,
                                    const float* __restrict__ h, const float* __restrict__ W,
                                    uint2* __restrict__ hw, int n) {
    __shared__ int cnt[NPB], pre[NPB], cur[NPB];
    int t = threadIdx.x;   // blockDim = 512
    int blk = blockIdx.x;
    if (blk < NBUCK) {
        int b = blk;
        int ebase = b * CAP;
        int ecnt  = gcurD[b] - ebase;
        cnt[t] = 0;
        __syncthreads();
        for (int i = t; i < ecnt; i += NPB)
            atomicAdd(&cnt[(int)(bufD[ebase + i] >> 17)], 1);
        __syncthreads();
        int v = cnt[t];
        pre[t] = v;
        __syncthreads();
        for (int off = 1; off < NPB; off <<= 1) {
            int x = (t >= off) ? pre[t - off] : 0;
            __syncthreads(); pre[t] += x; __syncthreads();
        }
        int excl = pre[t] - v;
        cur[t] = excl;
        int node = b * NPB + t;
        if (node < N_NODES) {
            offs[node] = make_int2(ebase + excl, ebase + excl + v);
            inv_in[node] = rsqrtf((float)max(v, 1));
        }
        __syncthreads();
        for (int i = t; i < ecnt; i += NPB) {
            unsigned en = bufD[ebase + i];
            int pos = atomicAdd(&cur[(int)(en >> 17)], 1);
            csr_src[ebase + pos] = (int)(en & 0x1FFFFu);
        }
    } else if (blk < 2 * NBUCK) {
        int b = blk - NBUCK;
        int ebase = b * CAP;
        int ecnt  = gcurS[b] - ebase;
        cnt[t] = 0;
        __syncthreads();
        for (int i = t; i < ecnt; i += NPB)
            atomicAdd(&cnt[(int)bufS[ebase + i]], 1);
        __syncthreads();
        int node = b * NPB + t;
        if (node < N_NODES) inv_out[node] = rsqrtf((float)max(cnt[t], 1));
    } else {
        dense_body512(t, (blk - 2 * NBUCK) * DROWS, h, W, hw, n);
    }
}

// ---------------- K3: fused layer-1 gather + layer-2 dense ----------------
// gather: h1 = relu(inv_in * sum inv_out[s]*hw_in[s] + b)   (h1 stays in registers)
// dense:  hw_out(fp16) = h1 @ W     (lane gl already holds cols [8gl,8gl+8))
__global__ void gather_dense_kernel(const uint4* __restrict__ hw_in, const float* __restrict__ inv_in,
                                    const float* __restrict__ inv_out,
                                    const int2* __restrict__ offs, const int* __restrict__ csr_src,
                                    const float* __restrict__ bias, const float* __restrict__ W,
                                    uint2* __restrict__ hw_out, int n) {
    __shared__ float Wlds[HDIM * HDIM];     // 16 KB
    int t = threadIdx.x;
    for (int i = t; i < HDIM * HDIM / 4; i += 256)
        ((f4v*)Wlds)[i] = ((const f4v*)W)[i];

    int wave = t >> 6, lane = t & 63;
    int g = lane >> 3, gl = lane & 7;
    int row = blockIdx.x * 32 + wave * 8 + g;  // N = 3125 * 32 exactly -> always valid

    float acc0 = 0.f, acc1 = 0.f, acc2 = 0.f, acc3 = 0.f;
    float acc4 = 0.f, acc5 = 0.f, acc6 = 0.f, acc7 = 0.f;

    int2 oe = offs[row];
    int start = oe.x, end = oe.y;
    int gbase = g << 3;

    int jb = start;
    int mm = end - jb; if (mm > 8) mm = 8;
    int sidx = (mm > 0 && gl < mm) ? csr_src[jb + gl] : 0;
    float sw = inv_out[sidx];

    while (jb < end) {
        int jb2 = jb + 8;
        int mm2 = end - jb2; if (mm2 > 8) mm2 = 8;
        int sidx2 = (jb2 < end && gl < mm2) ? csr_src[jb2 + gl] : 0;
        float sw2 = inv_out[sidx2];

        if (mm == 8) {
#pragma unroll
            for (int j = 0; j < 8; ++j) {
                int s = __shfl(sidx, gbase + j, 64);
                float w = __shfl(sw, gbase + j, 64);
                uint4 u = hw_in[(long long)s * 8 + gl];
                float2 f0 = __half22float2(*(__half2*)&u.x);
                float2 f1 = __half22float2(*(__half2*)&u.y);
                float2 f2 = __half22float2(*(__half2*)&u.z);
                float2 f3 = __half22float2(*(__half2*)&u.w);
                acc0 = fmaf(f0.x, w, acc0); acc1 = fmaf(f0.y, w, acc1);
                acc2 = fmaf(f1.x, w, acc2); acc3 = fmaf(f1.y, w, acc3);
                acc4 = fmaf(f2.x, w, acc4); acc5 = fmaf(f2.y, w, acc5);
                acc6 = fmaf(f3.x, w, acc6); acc7 = fmaf(f3.y, w, acc7);
            }
        } else {
            for (int j = 0; j < mm; ++j) {
                int s = __shfl(sidx, gbase + j, 64);
                float w = __shfl(sw, gbase + j, 64);
                uint4 u = hw_in[(long long)s * 8 + gl];
                float2 f0 = __half22float2(*(__half2*)&u.x);
                float2 f1 = __half22float2(*(__half2*)&u.y);
                float2 f2 = __half22float2(*(__half2*)&u.z);
                float2 f3 = __half22float2(*(__half2*)&u.w);
                acc0 = fmaf(f0.x, w, acc0); acc1 = fmaf(f0.y, w, acc1);
                acc2 = fmaf(f1.x, w, acc2); acc3 = fmaf(f1.y, w, acc3);
                acc4 = fmaf(f2.x, w, acc4); acc5 = fmaf(f2.y, w, acc5);
                acc6 = fmaf(f3.x, w, acc6); acc7 = fmaf(f3.y, w, acc7);
            }
        }
        jb = jb2; mm = mm2; sidx = sidx2; sw = sw2;
    }

    // finish layer 1 in registers: h1 = relu(acc*inv_in + bias)
    float sc = inv_in[row];
    float4 b0 = ((const float4*)bias)[gl * 2 + 0];
    float4 b1 = ((const float4*)bias)[gl * 2 + 1];
    f4v h0, h1;
    h0.x = fmaxf(fmaf(acc0, sc, b0.x), 0.f);
    h0.y = fmaxf(fmaf(acc1, sc, b0.y), 0.f);
    h0.z = fmaxf(fmaf(acc2, sc, b0.z), 0.f);
    h0.w = fmaxf(fmaf(acc3, sc, b0.w), 0.f);
    h1.x = fmaxf(fmaf(acc4, sc, b1.x), 0.f);
    h1.y = fmaxf(fmaf(acc5, sc, b1.y), 0.f);
    h1.z = fmaxf(fmaf(acc6, sc, b1.z), 0.f);
    h1.w = fmaxf(fmaf(acc7, sc, b1.w), 0.f);

    __syncthreads();   // Wlds ready (all lanes reach: no early returns)

    // layer-2 dense: hw_out = h1row @ W
    float d0 = 0.f, d1 = 0.f, d2 = 0.f, d3 = 0.f;
    float d4 = 0.f, d5 = 0.f, d6 = 0.f, d7 = 0.f;
#pragma unroll
    for (int k = 0; k < HDIM; ++k) {
        float av = ((k >> 2) & 1) ? h1[k & 3] : h0[k & 3];
        float ak = __shfl(av, gbase + (k >> 3), 64);
        f4v w0 = ((const f4v*)Wlds)[k * 16 + gl * 2 + 0];
        f4v w1 = ((const f4v*)Wlds)[k * 16 + gl * 2 + 1];
        d0 = fmaf(ak, w0.x, d0); d1 = fmaf(ak, w0.y, d1);
        d2 = fmaf(ak, w0.z, d2); d3 = fmaf(ak, w0.w, d3);
        d4 = fmaf(ak, w1.x, d4); d5 = fmaf(ak, w1.y, d5);
        d6 = fmaf(ak, w1.z, d6); d7 = fmaf(ak, w1.w, d7);
    }

    hw_out[(long long)row * 16 + gl * 2 + 0] = f4_to_h4(d0, d1, d2, d3);
    hw_out[(long long)row * 16 + gl * 2 + 1] = f4_to_h4(d4, d5, d6, d7);
}

// ---------------- K4: final gather: out = relu(inv_in * sum inv_out[s]*hw2[s] + b) ----------------
__global__ void gather_kernel(const uint4* __restrict__ hw, const float* __restrict__ inv_in,
                              const float* __restrict__ inv_out,
                              const int2* __restrict__ offs, const int* __restrict__ csr_src,
                              const float* __restrict__ bias, float* __restrict__ out, int n) {
    int t = threadIdx.x;
    int wave = t >> 6, lane = t & 63;
    int g = lane >> 3, gl = lane & 7;
    int row = blockIdx.x * 32 + wave * 8 + g;
    if (row >= n) return;

    float acc0 = 0.f, acc1 = 0.f, acc2 = 0.f, acc3 = 0.f;
    float acc4 = 0.f, acc5 = 0.f, acc6 = 0.f, acc7 = 0.f;

    int2 oe = offs[row];
    int start = oe.x, end = oe.y;
    int gbase = g << 3;

    int jb = start;
    int mm = end - jb; if (mm > 8) mm = 8;
    int sidx = (mm > 0 && gl < mm) ? csr_src[jb + gl] : 0;
    float sw = inv_out[sidx];

    while (jb < end) {
        int jb2 = jb + 8;
        int mm2 = end - jb2; if (mm2 > 8) mm2 = 8;
        int sidx2 = (jb2 < end && gl < mm2) ? csr_src[jb2 + gl] : 0;
        float sw2 = inv_out[sidx2];

        if (mm == 8) {
#pragma unroll
            for (int j = 0; j < 8; ++j) {
                int s = __shfl(sidx, gbase + j, 64);
                float w = __shfl(sw, gbase + j, 64);
                uint4 u = hw[(long long)s * 8 + gl];
                float2 f0 = __half22float2(*(__half2*)&u.x);
                float2 f1 = __half22float2(*(__half2*)&u.y);
                float2 f2 = __half22float2(*(__half2*)&u.z);
                float2 f3 = __half22float2(*(__half2*)&u.w);
                acc0 = fmaf(f0.x, w, acc0); acc1 = fmaf(f0.y, w, acc1);
                acc2 = fmaf(f1.x, w, acc2); acc3 = fmaf(f1.y, w, acc3);
                acc4 = fmaf(f2.x, w, acc4); acc5 = fmaf(f2.y, w, acc5);
                acc6 = fmaf(f3.x, w, acc6); acc7 = fmaf(f3.y, w, acc7);
            }
        } else {
            for (int j = 0; j < mm; ++j) {
                int s = __shfl(sidx, gbase + j, 64);
                float w = __shfl(sw, gbase + j, 64);
                uint4 u = hw[(long long)s * 8 + gl];
                float2 f0 = __half22float2(*(__half2*)&u.x);
                float2 f1 = __half22float2(*(__half2*)&u.y);
                float2 f2 = __half22float2(*(__half2*)&u.z);
                float2 f3 = __half22float2(*(__half2*)&u.w);
                acc0 = fmaf(f0.x, w, acc0); acc1 = fmaf(f0.y, w, acc1);
                acc2 = fmaf(f1.x, w, acc2); acc3 = fmaf(f1.y, w, acc3);
                acc4 = fmaf(f2.x, w, acc4); acc5 = fmaf(f2.y, w, acc5);
                acc6 = fmaf(f3.x, w, acc6); acc7 = fmaf(f3.y, w, acc7);
            }
        }
        jb = jb2; mm = mm2; sidx = sidx2; sw = sw2;
    }

    float sc = inv_in[row];
    float4 b0 = ((const float4*)bias)[gl * 2 + 0];
    float4 b1 = ((const float4*)bias)[gl * 2 + 1];
    f4v r0, r1;
    r0.x = fmaxf(fmaf(acc0, sc, b0.x), 0.f);
    r0.y = fmaxf(fmaf(acc1, sc, b0.y), 0.f);
    r0.z = fmaxf(fmaf(acc2, sc, b0.z), 0.f);
    r0.w = fmaxf(fmaf(acc3, sc, b0.w), 0.f);
    r1.x = fmaxf(fmaf(acc4, sc, b1.x), 0.f);
    r1.y = fmaxf(fmaf(acc5, sc, b1.y), 0.f);
    r1.z = fmaxf(fmaf(acc6, sc, b1.z), 0.f);
    r1.w = fmaxf(fmaf(acc7, sc, b1.w), 0.f);
    __builtin_nontemporal_store(r0, (f4v*)out + (long long)row * 16 + gl * 2 + 0);
    __builtin_nontemporal_store(r1, (f4v*)out + (long long)row * 16 + gl * 2 + 1);
}

extern "C" void kernel_launch(void* const* d_in, const int* in_sizes, int n_in,
                              void* d_out, int out_size, void* d_ws, size_t ws_size,
                              hipStream_t stream) {
    const float* features = (const float*)d_in[0];   // [N, 64]
    const float* W        = (const float*)d_in[1];   // [64, 64]
    const float* b        = (const float*)d_in[2];   // [64]
    const int*   src      = (const int*)d_in[3];     // [E]
    const int*   dst      = (const int*)d_in[4];     // [E]

    float* out = (float*)d_out;                      // [N, 64]

    // workspace layout (4-byte words); ~59 MB of 256 MB ws
    float* ws = (float*)d_ws;
    uint2* hw  = (uint2*)ws;                                            // N*32 words
    uint2* hw2 = (uint2*)(ws + (size_t)N_NODES * 32);                   // N*32 words
    unsigned int*   bufD = (unsigned int*)(ws + (size_t)N_NODES * 64);  // NBUCK*CAP words
    unsigned short* bufS = (unsigned short*)(bufD + (size_t)NBUCK * CAP); // NBUCK*CAP u16
    int*   csr_src = (int*)(bufS + (size_t)NBUCK * CAP);                // NBUCK*CAP words
    int2*  offs    = (int2*)(csr_src + (size_t)NBUCK * CAP);            // N int2
    float* inv_out = (float*)(offs + N_NODES);       // N
    float* inv_in  = inv_out + N_NODES;              // N
    int*   gcurD   = (int*)(inv_in + N_NODES);       // NBUCK
    int*   gcurS   = gcurD + NBUCK;                  // NBUCK

    const int N = N_NODES;
    int gather_blocks = (N + 31) / 32;   // 3125

    // K0: cursors
    init_kernel<<<1, 256, 0, stream>>>(gcurD, gcurS);

    // K1: edge placement SOLO (scatter kernel must not share L2 with a streaming kernel)
    place_kernel<<<NCHUNK, 256, 0, stream>>>(src, dst, gcurD, gcurS, bufD, bufS);

    // K2: per-bucket fine stage ∥ dense layer-1 (bucket uses 392 blocks; dense fills idle CUs)
    bucket_dense_kernel<<<2 * NBUCK + DENSE_BLOCKS, NPB, 0, stream>>>(
        bufD, bufS, gcurD, gcurS, csr_src, offs, inv_in, inv_out,
        features, W, hw, N);

    // K3: fused layer-1 gather + layer-2 dense -> hw2
    gather_dense_kernel<<<gather_blocks, 256, 0, stream>>>(
        (const uint4*)hw, inv_in, inv_out, offs, csr_src, b, W, hw2, N);

    // K4: final gather -> out
    gather_kernel<<<gather_blocks, 256, 0, stream>>>(
        (const uint4*)hw2, inv_in, inv_out, offs, csr_src, b, out, N);
}

// Round 4
// 229.939 us; speedup vs baseline: 1.1364x; 1.1364x over previous
//
#include <hip/hip_runtime.h>
#include <hip/hip_fp16.h>

#define N_NODES 100000
#define N_EDGES 1600000
#define HDIM 64
#define NPB 512                                  // nodes per bucket (pow2)
#define NPB_SHIFT 9
#define NBUCK 196                                // ceil(100000/512)
#define CAP 16384                                // per-bucket slot capacity
#define NCHUNK 256                               // place blocks (baseline-measured config)
#define CHUNK (N_EDGES / NCHUNK)                 // 6250 edges/block

typedef float f4v __attribute__((ext_vector_type(4)));

// ---------------- K0: init global bucket cursors ----------------
__global__ void init_kernel(int* __restrict__ gcurD, int* __restrict__ gcurS) {
    int t = threadIdx.x;
    if (t < NBUCK) {
        gcurD[t] = t * CAP;
        gcurS[t] = t * CAP;
    }
}

__device__ inline uint2 f4_to_h4(float x, float y, float z, float w) {
    __half2 lo = __floats2half2_rn(x, y);
    __half2 hi = __floats2half2_rn(z, w);
    uint2 r;
    r.x = *(unsigned*)&lo;
    r.y = *(unsigned*)&hi;
    return r;
}

// ---------------- K1: place edges into fixed-capacity bucket regions (SOLO) ----------------
// Run reservation: one global atomic per (chunk,bucket); scatter via LDS cursors.
// bufD entry: src | (local_dst << 17)
__global__ void place_kernel(const int* __restrict__ src, const int* __restrict__ dst,
                             int* __restrict__ gcurD, int* __restrict__ gcurS,
                             unsigned int* __restrict__ bufD, unsigned short* __restrict__ bufS) {
    __shared__ int hD[NBUCK], hS[NBUCK], curD[NBUCK], curS[NBUCK];
    int t = threadIdx.x, blk = blockIdx.x;
    for (int i = t; i < NBUCK; i += 256) { hD[i] = 0; hS[i] = 0; }
    __syncthreads();
    int e0 = blk * CHUNK;
    // pass 1: count (chunk is ~50 KB -> L1/L2 hot for pass 2)
    for (int i = t; i < CHUNK; i += 256) {
        atomicAdd(&hD[dst[e0 + i] >> NPB_SHIFT], 1);
        atomicAdd(&hS[src[e0 + i] >> NPB_SHIFT], 1);
    }
    __syncthreads();
    // reserve runs
    for (int i = t; i < NBUCK; i += 256) {
        curD[i] = hD[i] ? atomicAdd(&gcurD[i], hD[i]) : 0;
        curS[i] = hS[i] ? atomicAdd(&gcurS[i], hS[i]) : 0;
    }
    __syncthreads();
    // pass 2: scatter
    for (int i = t; i < CHUNK; i += 256) {
        int s = src[e0 + i], d = dst[e0 + i];
        int pd = atomicAdd(&curD[d >> NPB_SHIFT], 1);
        bufD[pd] = (unsigned)s | ((unsigned)(d & (NPB - 1)) << 17);
        int ps = atomicAdd(&curS[s >> NPB_SHIFT], 1);
        bufS[ps] = (unsigned short)(s & (NPB - 1));
    }
}

// ---------------- K2: merged per-bucket fine stage ----------------
// blocks [0,196): dst buckets -> counting sort to csr_src, offs(int2), inv_in
// blocks [196,392): src buckets -> counts -> inv_out
__global__ void bucket_kernel(const unsigned int* __restrict__ bufD,
                              const unsigned short* __restrict__ bufS,
                              const int* __restrict__ gcurD, const int* __restrict__ gcurS,
                              int* __restrict__ csr_src, int2* __restrict__ offs,
                              float* __restrict__ inv_in, float* __restrict__ inv_out) {
    __shared__ int cnt[NPB], pre[NPB], cur[NPB];
    int t = threadIdx.x;   // blockDim = 512
    int blk = blockIdx.x;
    if (blk < NBUCK) {
        int b = blk;
        int ebase = b * CAP;
        int ecnt  = gcurD[b] - ebase;
        cnt[t] = 0;
        __syncthreads();
        for (int i = t; i < ecnt; i += NPB)
            atomicAdd(&cnt[(int)(bufD[ebase + i] >> 17)], 1);
        __syncthreads();
        int v = cnt[t];
        pre[t] = v;
        __syncthreads();
        for (int off = 1; off < NPB; off <<= 1) {
            int x = (t >= off) ? pre[t - off] : 0;
            __syncthreads(); pre[t] += x; __syncthreads();
        }
        int excl = pre[t] - v;
        cur[t] = excl;
        int node = b * NPB + t;
        if (node < N_NODES) {
            offs[node] = make_int2(ebase + excl, ebase + excl + v);
            inv_in[node] = rsqrtf((float)max(v, 1));
        }
        __syncthreads();
        for (int i = t; i < ecnt; i += NPB) {
            unsigned en = bufD[ebase + i];
            int pos = atomicAdd(&cur[(int)(en >> 17)], 1);
            csr_src[ebase + pos] = (int)(en & 0x1FFFFu);
        }
    } else {
        int b = blk - NBUCK;
        int ebase = b * CAP;
        int ecnt  = gcurS[b] - ebase;
        cnt[t] = 0;
        __syncthreads();
        for (int i = t; i < ecnt; i += NPB)
            atomicAdd(&cnt[(int)bufS[ebase + i]], 1);
        __syncthreads();
        int node = b * NPB + t;
        if (node < N_NODES) inv_out[node] = rsqrtf((float)max(cnt[t], 1));
    }
}

// ---------------- K3: dense (baseline-style): hw(fp16) = (h * inv_out[:,None]) @ W ----------------
// 32 rows/block, 256 threads, Alds staging (the measured-best dense structure).
__global__ void dense_kernel(const float* __restrict__ h, const float* __restrict__ inv_out,
                             const float* __restrict__ W, uint2* __restrict__ hw, int n) {
    __shared__ float Wlds[HDIM * HDIM];     // 16 KB
    __shared__ float Alds[32][HDIM + 1];    // 8.1 KB
    int t = threadIdx.x;
    int r0 = blockIdx.x * 32;

    for (int i = t; i < HDIM * HDIM / 4; i += 256)
        ((f4v*)Wlds)[i] = ((const f4v*)W)[i];

    for (int i = t; i < 512; i += 256) {    // 32 rows x 16 float4
        int r = i >> 4;
        int c4 = i & 15;
        int row = r0 + r;
        f4v v = {0.f, 0.f, 0.f, 0.f};
        float s = 0.f;
        if (row < n) {
            v = __builtin_nontemporal_load((const f4v*)h + (long long)row * 16 + c4);
            s = inv_out[row];
        }
        Alds[r][c4 * 4 + 0] = v.x * s;
        Alds[r][c4 * 4 + 1] = v.y * s;
        Alds[r][c4 * 4 + 2] = v.z * s;
        Alds[r][c4 * 4 + 3] = v.w * s;
    }
    __syncthreads();

    int tx = t & 15;        // col quad
    int ty = t >> 4;        // 16 row-pairs
    float4 acc0 = make_float4(0.f, 0.f, 0.f, 0.f);
    float4 acc1 = acc0;

#pragma unroll 8
    for (int k = 0; k < HDIM; ++k) {
        f4v w = ((const f4v*)(Wlds + k * HDIM))[tx];
        float a0 = Alds[2 * ty + 0][k];
        float a1 = Alds[2 * ty + 1][k];
        acc0.x = fmaf(a0, w.x, acc0.x); acc0.y = fmaf(a0, w.y, acc0.y);
        acc0.z = fmaf(a0, w.z, acc0.z); acc0.w = fmaf(a0, w.w, acc0.w);
        acc1.x = fmaf(a1, w.x, acc1.x); acc1.y = fmaf(a1, w.y, acc1.y);
        acc1.z = fmaf(a1, w.z, acc1.z); acc1.w = fmaf(a1, w.w, acc1.w);
    }

    int rb = r0 + 2 * ty;
    if (rb + 0 < n) hw[(long long)(rb + 0) * 16 + tx] = f4_to_h4(acc0.x, acc0.y, acc0.z, acc0.w);
    if (rb + 1 < n) hw[(long long)(rb + 1) * 16 + tx] = f4_to_h4(acc1.x, acc1.y, acc1.z, acc1.w);
}

// ---------------- K4: fused layer-1 gather + layer-2 dense ----------------
// gather (baseline inner loop, hw pre-scaled so NO per-edge scale):
//   h1 = relu(inv_in[row] * sum hw[s] + b)          (h1 stays in registers)
// epilogue dense (per-ROW scale only):
//   hw2[row] = inv_out[row] * (h1 @ W)   via intra-wave shfl; lane gl owns cols [8gl,8gl+8)
// Saves the 25.6MB out write + 25.6MB read-back + one dispatch vs baseline.
__global__ void gather_dense_kernel(const uint4* __restrict__ hw_in, const float* __restrict__ inv_in,
                                    const float* __restrict__ inv_out,
                                    const int2* __restrict__ offs, const int* __restrict__ csr_src,
                                    const float* __restrict__ bias, const float* __restrict__ W,
                                    uint2* __restrict__ hw_out, int n) {
    __shared__ float Wlds[HDIM * HDIM];     // 16 KB
    int t = threadIdx.x;
    for (int i = t; i < HDIM * HDIM / 4; i += 256)
        ((f4v*)Wlds)[i] = ((const f4v*)W)[i];

    int wave = t >> 6, lane = t & 63;
    int g = lane >> 3, gl = lane & 7;          // group 0..7, lane-in-group 0..7
    int row = blockIdx.x * 32 + wave * 8 + g;  // N = 3125 * 32 exactly -> always valid

    float acc0 = 0.f, acc1 = 0.f, acc2 = 0.f, acc3 = 0.f;
    float acc4 = 0.f, acc5 = 0.f, acc6 = 0.f, acc7 = 0.f;

    int2 oe = offs[row];
    int start = oe.x, end = oe.y;
    int gbase = g << 3;

    int jb = start;
    int mm = end - jb; if (mm > 8) mm = 8;
    int sidx = (mm > 0 && gl < mm) ? csr_src[jb + gl] : 0;

    while (jb < end) {
        int jb2 = jb + 8;
        int mm2 = end - jb2; if (mm2 > 8) mm2 = 8;
        int sidx2 = (jb2 < end && gl < mm2) ? csr_src[jb2 + gl] : 0;

        if (mm == 8) {
#pragma unroll
            for (int j = 0; j < 8; ++j) {
                int s = __shfl(sidx, gbase + j, 64);
                uint4 u = hw_in[(long long)s * 8 + gl];
                float2 f0 = __half22float2(*(__half2*)&u.x);
                float2 f1 = __half22float2(*(__half2*)&u.y);
                float2 f2 = __half22float2(*(__half2*)&u.z);
                float2 f3 = __half22float2(*(__half2*)&u.w);
                acc0 += f0.x; acc1 += f0.y; acc2 += f1.x; acc3 += f1.y;
                acc4 += f2.x; acc5 += f2.y; acc6 += f3.x; acc7 += f3.y;
            }
        } else {
            for (int j = 0; j < mm; ++j) {
                int s = __shfl(sidx, gbase + j, 64);
                uint4 u = hw_in[(long long)s * 8 + gl];
                float2 f0 = __half22float2(*(__half2*)&u.x);
                float2 f1 = __half22float2(*(__half2*)&u.y);
                float2 f2 = __half22float2(*(__half2*)&u.z);
                float2 f3 = __half22float2(*(__half2*)&u.w);
                acc0 += f0.x; acc1 += f0.y; acc2 += f1.x; acc3 += f1.y;
                acc4 += f2.x; acc5 += f2.y; acc6 += f3.x; acc7 += f3.y;
            }
        }
        jb = jb2; mm = mm2; sidx = sidx2;
    }

    // finish layer 1 in registers: h1 = relu(acc*inv_in + bias), then pre-scale by inv_out[row]
    float sc = inv_in[row];
    float so = inv_out[row];                   // per-ROW scalar (not per-edge!)
    float4 b0 = ((const float4*)bias)[gl * 2 + 0];
    float4 b1 = ((const float4*)bias)[gl * 2 + 1];
    f4v h0, h1;
    h0.x = fmaxf(fmaf(acc0, sc, b0.x), 0.f) * so;
    h0.y = fmaxf(fmaf(acc1, sc, b0.y), 0.f) * so;
    h0.z = fmaxf(fmaf(acc2, sc, b0.z), 0.f) * so;
    h0.w = fmaxf(fmaf(acc3, sc, b0.w), 0.f) * so;
    h1.x = fmaxf(fmaf(acc4, sc, b1.x), 0.f) * so;
    h1.y = fmaxf(fmaf(acc5, sc, b1.y), 0.f) * so;
    h1.z = fmaxf(fmaf(acc6, sc, b1.z), 0.f) * so;
    h1.w = fmaxf(fmaf(acc7, sc, b1.w), 0.f) * so;

    __syncthreads();   // Wlds ready (all lanes reach here: no early returns)

    // layer-2 dense: hw_out[row] = (inv_out[row]*h1row) @ W
    float d0 = 0.f, d1 = 0.f, d2 = 0.f, d3 = 0.f;
    float d4 = 0.f, d5 = 0.f, d6 = 0.f, d7 = 0.f;
#pragma unroll
    for (int k = 0; k < HDIM; ++k) {
        float av = ((k >> 2) & 1) ? h1[k & 3] : h0[k & 3];   // static component
        float ak = __shfl(av, gbase + (k >> 3), 64);
        f4v w0 = ((const f4v*)Wlds)[k * 16 + gl * 2 + 0];
        f4v w1 = ((const f4v*)Wlds)[k * 16 + gl * 2 + 1];
        d0 = fmaf(ak, w0.x, d0); d1 = fmaf(ak, w0.y, d1);
        d2 = fmaf(ak, w0.z, d2); d3 = fmaf(ak, w0.w, d3);
        d4 = fmaf(ak, w1.x, d4); d5 = fmaf(ak, w1.y, d5);
        d6 = fmaf(ak, w1.z, d6); d7 = fmaf(ak, w1.w, d7);
    }

    hw_out[(long long)row * 16 + gl * 2 + 0] = f4_to_h4(d0, d1, d2, d3);
    hw_out[(long long)row * 16 + gl * 2 + 1] = f4_to_h4(d4, d5, d6, d7);
}

// ---------------- K5: final gather: out = relu(inv_in * sum hw2[s] + b) ----------------
// hw2 rows are pre-scaled by inv_out -> baseline-clean inner loop.
__global__ void gather_kernel(const uint4* __restrict__ hw, const float* __restrict__ inv_in,
                              const int2* __restrict__ offs, const int* __restrict__ csr_src,
                              const float* __restrict__ bias, float* __restrict__ out, int n) {
    int t = threadIdx.x;
    int wave = t >> 6, lane = t & 63;
    int g = lane >> 3, gl = lane & 7;
    int row = blockIdx.x * 32 + wave * 8 + g;
    if (row >= n) return;

    float acc0 = 0.f, acc1 = 0.f, acc2 = 0.f, acc3 = 0.f;
    float acc4 = 0.f, acc5 = 0.f, acc6 = 0.f, acc7 = 0.f;

    int2 oe = offs[row];
    int start = oe.x, end = oe.y;
    int gbase = g << 3;

    int jb = start;
    int mm = end - jb; if (mm > 8) mm = 8;
    int sidx = (mm > 0 && gl < mm) ? csr_src[jb + gl] : 0;

    while (jb < end) {
        int jb2 = jb + 8;
        int mm2 = end - jb2; if (mm2 > 8) mm2 = 8;
        int sidx2 = (jb2 < end && gl < mm2) ? csr_src[jb2 + gl] : 0;

        if (mm == 8) {
#pragma unroll
            for (int j = 0; j < 8; ++j) {
                int s = __shfl(sidx, gbase + j, 64);
                uint4 u = hw[(long long)s * 8 + gl];
                float2 f0 = __half22float2(*(__half2*)&u.x);
                float2 f1 = __half22float2(*(__half2*)&u.y);
                float2 f2 = __half22float2(*(__half2*)&u.z);
                float2 f3 = __half22float2(*(__half2*)&u.w);
                acc0 += f0.x; acc1 += f0.y; acc2 += f1.x; acc3 += f1.y;
                acc4 += f2.x; acc5 += f2.y; acc6 += f3.x; acc7 += f3.y;
            }
        } else {
            for (int j = 0; j < mm; ++j) {
                int s = __shfl(sidx, gbase + j, 64);
                uint4 u = hw[(long long)s * 8 + gl];
                float2 f0 = __half22float2(*(__half2*)&u.x);
                float2 f1 = __half22float2(*(__half2*)&u.y);
                float2 f2 = __half22float2(*(__half2*)&u.z);
                float2 f3 = __half22float2(*(__half2*)&u.w);
                acc0 += f0.x; acc1 += f0.y; acc2 += f1.x; acc3 += f1.y;
                acc4 += f2.x; acc5 += f2.y; acc6 += f3.x; acc7 += f3.y;
            }
        }
        jb = jb2; mm = mm2; sidx = sidx2;
    }

    float sc = inv_in[row];
    float4 b0 = ((const float4*)bias)[gl * 2 + 0];
    float4 b1 = ((const float4*)bias)[gl * 2 + 1];
    f4v r0, r1;
    r0.x = fmaxf(fmaf(acc0, sc, b0.x), 0.f);
    r0.y = fmaxf(fmaf(acc1, sc, b0.y), 0.f);
    r0.z = fmaxf(fmaf(acc2, sc, b0.z), 0.f);
    r0.w = fmaxf(fmaf(acc3, sc, b0.w), 0.f);
    r1.x = fmaxf(fmaf(acc4, sc, b1.x), 0.f);
    r1.y = fmaxf(fmaf(acc5, sc, b1.y), 0.f);
    r1.z = fmaxf(fmaf(acc6, sc, b1.z), 0.f);
    r1.w = fmaxf(fmaf(acc7, sc, b1.w), 0.f);
    __builtin_nontemporal_store(r0, (f4v*)out + (long long)row * 16 + gl * 2 + 0);
    __builtin_nontemporal_store(r1, (f4v*)out + (long long)row * 16 + gl * 2 + 1);
}

extern "C" void kernel_launch(void* const* d_in, const int* in_sizes, int n_in,
                              void* d_out, int out_size, void* d_ws, size_t ws_size,
                              hipStream_t stream) {
    const float* features = (const float*)d_in[0];   // [N, 64]
    const float* W        = (const float*)d_in[1];   // [64, 64]
    const float* b        = (const float*)d_in[2];   // [64]
    const int*   src      = (const int*)d_in[3];     // [E]
    const int*   dst      = (const int*)d_in[4];     // [E]

    float* out = (float*)d_out;                      // [N, 64]

    // workspace layout (4-byte words); ~59 MB of 256 MB ws
    float* ws = (float*)d_ws;
    uint2* hw  = (uint2*)ws;                                            // N*32 words
    uint2* hw2 = (uint2*)(ws + (size_t)N_NODES * 32);                   // N*32 words
    unsigned int*   bufD = (unsigned int*)(ws + (size_t)N_NODES * 64);  // NBUCK*CAP words
    unsigned short* bufS = (unsigned short*)(bufD + (size_t)NBUCK * CAP); // NBUCK*CAP u16
    int*   csr_src = (int*)(bufS + (size_t)NBUCK * CAP);                // NBUCK*CAP words
    int2*  offs    = (int2*)(csr_src + (size_t)NBUCK * CAP);            // N int2
    float* inv_out = (float*)(offs + N_NODES);       // N
    float* inv_in  = inv_out + N_NODES;              // N
    int*   gcurD   = (int*)(inv_in + N_NODES);       // NBUCK
    int*   gcurS   = gcurD + NBUCK;                  // NBUCK

    const int N = N_NODES;
    int dense_blocks  = (N + 31) / 32;   // 3125
    int gather_blocks = (N + 31) / 32;   // 3125

    // K0: cursors
    init_kernel<<<1, 256, 0, stream>>>(gcurD, gcurS);

    // K1: edge placement SOLO (baseline config — no co-launched streaming kernel)
    place_kernel<<<NCHUNK, 256, 0, stream>>>(src, dst, gcurD, gcurS, bufD, bufS);

    // K2: per-bucket fine stage (csr, offs, inv_in, inv_out)
    bucket_kernel<<<2 * NBUCK, NPB, 0, stream>>>(bufD, bufS, gcurD, gcurS,
                                                 csr_src, offs, inv_in, inv_out);

    // K3: dense layer-1 (inv_out scale applied here, baseline-style) -> hw
    dense_kernel<<<dense_blocks, 256, 0, stream>>>(features, inv_out, W, hw, N);

    // K4: fused layer-1 gather + layer-2 dense -> hw2 (out round-trip eliminated)
    gather_dense_kernel<<<gather_blocks, 256, 0, stream>>>(
        (const uint4*)hw, inv_in, inv_out, offs, csr_src, b, W, hw2, N);

    // K5: final gather -> out
    gather_kernel<<<gather_blocks, 256, 0, stream>>>(
        (const uint4*)hw2, inv_in, offs, csr_src, b, out, N);
}